// Round 8
// baseline (874.080 us; speedup 1.0000x reference)
//
#include <hip/hip_runtime.h>
#include <hip/hip_fp16.h>
#include <math.h>

#define BB 512   // batch
#define TT 1024  // max seq len
#define HH 128   // hidden

// ---------------------------------------------------------------------------
// Kernel 1: bitonic sort of (length, idx) composite keys, descending.
// Load-balance only; any permutation is still correct.
// ---------------------------------------------------------------------------
__global__ __launch_bounds__(512) void sort_kernel(const int* __restrict__ lengths,
                                                   int* __restrict__ order) {
  __shared__ int comp[BB];
  const int t = threadIdx.x;
  comp[t] = (lengths[t] << 9) | t;  // unique composite keys
  __syncthreads();
  for (int k = 2; k <= BB; k <<= 1) {
    for (int j = k >> 1; j > 0; j >>= 1) {
      int ixj = t ^ j;
      if (ixj > t) {
        int a = comp[t], b = comp[ixj];
        bool descBlock = ((t & k) == 0);
        bool doSwap = descBlock ? (a < b) : (a > b);
        if (doSwap) { comp[t] = b; comp[ixj] = a; }
      }
      __syncthreads();
    }
  }
  order[t] = comp[t] & 511;
}

// single-instruction mixed-precision FMA helpers:
//   acc(f32) += f16(lo/hi of w) * h(f32)
__device__ __forceinline__ void fma_lo(float& acc, unsigned int w, float h) {
  asm volatile("v_fma_mix_f32 %0, %1, %2, %0 op_sel:[0,0,0] op_sel_hi:[1,0,0]"
               : "+v"(acc) : "v"(w), "v"(h));
}
__device__ __forceinline__ void fma_hi(float& acc, unsigned int w, float h) {
  asm volatile("v_fma_mix_f32 %0, %1, %2, %0 op_sel:[1,0,0] op_sel_hi:[1,0,0]"
               : "+v"(acc) : "v"(w), "v"(h));
}

// ---------------------------------------------------------------------------
// Kernel 2: GRU recurrence. 256 blocks x 1024 threads (16 waves), 1 block/CU.
// Thread (i = tid&127, kc = tid>>7): 16-wide K-chunk, weights held as
// 24 PACKED fp16 VGPRs, consumed by per-instruction v_fma_mix_f32 asm.
//
// ROUND HISTORY:
//   r1-r6: fp32-resident weights (48-96 regs) always spilled/sank -> L2
//          stream ~1700 cyc/step plateau.
//   r7:    fp16-packed 24 regs DID shrink the live set (VGPR=52 ~ live), but
//          a 13-operand mega-asm serialized 4 LDS-latency-gated blocks ->
//          slower. This round: per-instr asm, phase-2 consts -> LDS (cbuf),
//          long-lived regs = 24 packed weights only (live ~47 < 52).
// ---------------------------------------------------------------------------
__global__ __launch_bounds__(1024)
__attribute__((amdgpu_waves_per_eu(4, 4)))
void gru_main(
    const float* __restrict__ x, const int* __restrict__ lengths,
    const float* __restrict__ w_ih, const float* __restrict__ w_hh,
    const float* __restrict__ b_ih, const float* __restrict__ b_hh,
    const float* __restrict__ head_w, const float* __restrict__ head_b,
    const int* __restrict__ order, float* __restrict__ out) {
  __shared__ __align__(16) float hs[HH];        // current hidden state (fp32)
  __shared__ float parts[3][8][HH];             // split-K partials (12 KB)
  __shared__ __align__(16) float xrow[TT * 2];  // staged x row (8 KB)
  __shared__ float cbuf[HH * 11];               // phase-2 consts, stride 11

  const int tid = threadIdx.x;
  const int i  = tid & (HH - 1);  // output row within a gate
  const int kc = tid >> 7;        // k-chunk 0..7 (16 floats), wave-uniform

  // --- one-time: weights -> fp16 RTN, packed 2/VGPR (24 regs), pinned ---
  unsigned int wp[3][8];  // wp[g][q] = halves {w_hh[g*128+i][kc*16+2q], +2q+1}
#pragma unroll
  for (int g = 0; g < 3; ++g)
#pragma unroll
    for (int q = 0; q < 8; ++q) {
      const float w0 = w_hh[(g * HH + i) * HH + kc * 16 + 2 * q + 0];
      const float w1 = w_hh[(g * HH + i) * HH + kc * 16 + 2 * q + 1];
      __half2 h2;
      h2.x = __float2half(w0);  // RTN
      h2.y = __float2half(w1);
      wp[g][q] = *reinterpret_cast<unsigned int*>(&h2);
      asm volatile("" : "+v"(wp[g][q]));  // opaque def: no remat
    }

  // --- one-time: phase-2 constants into LDS (frees 14 long-lived VGPRs) ---
  if (tid < HH) {
    float* cb = &cbuf[tid * 11];
    cb[0] = w_ih[(0 * HH + tid) * 2 + 0];
    cb[1] = w_ih[(1 * HH + tid) * 2 + 0];
    cb[2] = w_ih[(2 * HH + tid) * 2 + 0];
    cb[3] = w_ih[(0 * HH + tid) * 2 + 1];
    cb[4] = w_ih[(1 * HH + tid) * 2 + 1];
    cb[5] = w_ih[(2 * HH + tid) * 2 + 1];
    cb[6] = b_ih[0 * HH + tid] + b_hh[0 * HH + tid];  // r: biases always summed
    cb[7] = b_ih[1 * HH + tid] + b_hh[1 * HH + tid];  // z: biases always summed
    cb[8] = b_ih[2 * HH + tid];                       // n: input-side bias
    cb[9] = b_hh[2 * HH + tid];                       // n: hidden-side bias
    cb[10] = head_w[tid];
  }

  for (int pb = 0; pb < 2; ++pb) {
    const int slot = pb ? (BB - 1 - (int)blockIdx.x) : (int)blockIdx.x;
    const int b = order[slot];
    const int len = lengths[b];  // in [1, 1024]

    // stage this batch's x row (coalesced) + init h
    for (int ofs = tid; ofs < len * 2; ofs += 1024)
      xrow[ofs] = x[(size_t)b * (TT * 2) + ofs];
    if (tid < HH) hs[tid] = 0.0f;
    __syncthreads();  // also covers cbuf visibility on pb==0

    const float* hbase = &hs[kc * 16];

    for (int t = 0; t < len; ++t) {
      // ---- phase 1: split-K matvec, packed-fp16 weights, fp32 h ----
      float pr = 0.f, pz = 0.f, pn = 0.f;
      float4 h0 = *reinterpret_cast<const float4*>(hbase + 0);
      float4 h1 = *reinterpret_cast<const float4*>(hbase + 4);
      // chunk 0 (k = kc*16 + 0..3)
      fma_lo(pr, wp[0][0], h0.x); fma_lo(pz, wp[1][0], h0.x); fma_lo(pn, wp[2][0], h0.x);
      fma_hi(pr, wp[0][0], h0.y); fma_hi(pz, wp[1][0], h0.y); fma_hi(pn, wp[2][0], h0.y);
      fma_lo(pr, wp[0][1], h0.z); fma_lo(pz, wp[1][1], h0.z); fma_lo(pn, wp[2][1], h0.z);
      fma_hi(pr, wp[0][1], h0.w); fma_hi(pz, wp[1][1], h0.w); fma_hi(pn, wp[2][1], h0.w);
      float4 h2 = *reinterpret_cast<const float4*>(hbase + 8);
      // chunk 1 (k = kc*16 + 4..7)
      fma_lo(pr, wp[0][2], h1.x); fma_lo(pz, wp[1][2], h1.x); fma_lo(pn, wp[2][2], h1.x);
      fma_hi(pr, wp[0][2], h1.y); fma_hi(pz, wp[1][2], h1.y); fma_hi(pn, wp[2][2], h1.y);
      fma_lo(pr, wp[0][3], h1.z); fma_lo(pz, wp[1][3], h1.z); fma_lo(pn, wp[2][3], h1.z);
      fma_hi(pr, wp[0][3], h1.w); fma_hi(pz, wp[1][3], h1.w); fma_hi(pn, wp[2][3], h1.w);
      float4 h3 = *reinterpret_cast<const float4*>(hbase + 12);
      // chunk 2 (k = kc*16 + 8..11)
      fma_lo(pr, wp[0][4], h2.x); fma_lo(pz, wp[1][4], h2.x); fma_lo(pn, wp[2][4], h2.x);
      fma_hi(pr, wp[0][4], h2.y); fma_hi(pz, wp[1][4], h2.y); fma_hi(pn, wp[2][4], h2.y);
      fma_lo(pr, wp[0][5], h2.z); fma_lo(pz, wp[1][5], h2.z); fma_lo(pn, wp[2][5], h2.z);
      fma_hi(pr, wp[0][5], h2.w); fma_hi(pz, wp[1][5], h2.w); fma_hi(pn, wp[2][5], h2.w);
      // chunk 3 (k = kc*16 + 12..15)
      fma_lo(pr, wp[0][6], h3.x); fma_lo(pz, wp[1][6], h3.x); fma_lo(pn, wp[2][6], h3.x);
      fma_hi(pr, wp[0][6], h3.y); fma_hi(pz, wp[1][6], h3.y); fma_hi(pn, wp[2][6], h3.y);
      fma_lo(pr, wp[0][7], h3.z); fma_lo(pz, wp[1][7], h3.z); fma_lo(pn, wp[2][7], h3.z);
      fma_hi(pr, wp[0][7], h3.w); fma_hi(pz, wp[1][7], h3.w); fma_hi(pn, wp[2][7], h3.w);

      parts[0][kc][i] = pr;
      parts[1][kc][i] = pz;
      parts[2][kc][i] = pn;
      __syncthreads();

      // ---- phase 2: reduce 8 partials/gate + gates + h update (tid<128) ----
      if (tid < HH) {
        float gr = 0.f, gz = 0.f, gn = 0.f;
#pragma unroll
        for (int c = 0; c < 8; ++c) gr += parts[0][c][tid];
#pragma unroll
        for (int c = 0; c < 8; ++c) gz += parts[1][c][tid];
#pragma unroll
        for (int c = 0; c < 8; ++c) gn += parts[2][c][tid];
        const float* cb = &cbuf[tid * 11];
        const float x0 = xrow[t * 2 + 0];
        const float x1 = xrow[t * 2 + 1];
        const float ar = cb[6] + x0 * cb[0] + x1 * cb[3] + gr;
        const float az = cb[7] + x0 * cb[1] + x1 * cb[4] + gz;
        const float an = cb[8] + x0 * cb[2] + x1 * cb[5];
        const float hn = gn + cb[9];
        const float r = 1.0f / (1.0f + __expf(-ar));
        const float z = 1.0f / (1.0f + __expf(-az));
        const float a = an + r * hn;          // tanh argument
        const float e2 = __expf(-2.0f * a);
        const float n = (1.0f - e2) / (1.0f + e2);
        hs[tid] = (1.0f - z) * n + z * hs[tid];
      }
      __syncthreads();
    }

    // ---- head: out[b] = dot(h, head_w) + head_b ----
    if (tid < HH) parts[0][0][tid] = hs[tid] * cbuf[tid * 11 + 10];
    __syncthreads();
    if (tid == 0) {
      float s = head_b[0];
      for (int q = 0; q < HH; ++q) s += parts[0][0][q];
      out[b] = s;
    }
    __syncthreads();  // protect hs/parts before next batch reuses them
  }
}

extern "C" void kernel_launch(void* const* d_in, const int* in_sizes, int n_in,
                              void* d_out, int out_size, void* d_ws, size_t ws_size,
                              hipStream_t stream) {
  const float* x       = (const float*)d_in[0];
  const int*   lengths = (const int*)d_in[1];
  const float* w_ih    = (const float*)d_in[2];
  const float* w_hh    = (const float*)d_in[3];
  const float* b_ih    = (const float*)d_in[4];
  const float* b_hh    = (const float*)d_in[5];
  const float* head_w  = (const float*)d_in[6];
  const float* head_b  = (const float*)d_in[7];
  float* out = (float*)d_out;
  int* order = (int*)d_ws;  // 512 ints of scratch

  sort_kernel<<<1, 512, 0, stream>>>(lengths, order);
  gru_main<<<256, 1024, 0, stream>>>(x, lengths, w_ih, w_hh, b_ih, b_hh,
                                     head_w, head_b, order, out);
}